// Round 1
// baseline (158.695 us; speedup 1.0000x reference)
//
#include <hip/hip_runtime.h>

// Bicubic x0.5 antialiased resize, (32,3,512,512) f32 -> (32,3,256,256) f32.
// Separable 8-tap stride-2 convolution; weights identical for every output
// position (wt[i*256]); source index = mirror(2*o + i - 3). Fused H-pass
// (global->LDS) + W-pass (LDS->global), one kernel, no workspace.
//
// This revision vs. the 157 µs version:
//  * full-width tile (512 input cols) -> every thread owns exactly 2 adjacent
//    columns: one aligned float2 (8 B/lane) load per input row instead of
//    scalar 4 B loads + a ragged 262-vs-256 second loop trip.
//  * column mirror halo comes free from registers (H-pass commutes with the
//    column mirror: mid[g=-1]==mid[g=0], etc.) -> no mirrored reloads.
//  * no column-tile split -> zero column halo re-reads.
//  * nontemporal output stores (output is never re-read; keep L2 for the
//    row-halo reuse between adjacent row tiles).

#define H_IN   512
#define W_IN   512
#define H_OUT  256
#define W_OUT  256
#define BC     96          // 32 batch * 3 channels
#define TAPS   8
#define OH_T   8           // output rows per block
#define IN_ROWS (2 * OH_T + 6)   // 22 input rows per block
#define MID_W  520         // mid col index c = g + 4, g in [-3 .. 514] -> c in [1..518]

__device__ __forceinline__ int mir(int r, int n) {
    // mirror boundary, valid for r in [-n, 2n-1]
    r = (r < 0) ? (-1 - r) : r;
    r = (r >= n) ? (2 * n - 1 - r) : r;
    return r;
}

__global__ __launch_bounds__(256) void resize_fused(const float* __restrict__ in,
                                                    const float* __restrict__ wt,
                                                    float* __restrict__ out) {
    __shared__ float mid[OH_T][MID_W];   // 16.25 KB

    const int bid = blockIdx.x;
    const int oht = bid & 31;            // 32 row tiles
    const int bc  = bid >> 5;            // 96 images
    const int oh0 = oht * OH_T;
    const int t   = threadIdx.x;

    float K[TAPS];
#pragma unroll
    for (int i = 0; i < TAPS; ++i) K[i] = wt[i * H_OUT];  // constant over output pos

    const float* src = in + (size_t)bc * H_IN * W_IN;
    const int rbase = 2 * oh0 - 3;
    const int g0 = 2 * t;                // this thread's two input columns

    // ---- Phase A: H-pass. One aligned float2 per input row; rolling register
    // window so each input element is read exactly once per block.
    float2 acc[OH_T];
#pragma unroll
    for (int k = 0; k < OH_T; ++k) acc[k] = make_float2(0.f, 0.f);

#pragma unroll
    for (int r = 0; r < IN_ROWS; ++r) {
        const int gr = mir(rbase + r, H_IN);   // uniform across the wave
        const float2 x = *reinterpret_cast<const float2*>(src + (size_t)gr * W_IN + g0);
#pragma unroll
        for (int k = 0; k < OH_T; ++k) {
            const int i = r - 2 * k;           // resolved at compile time
            if (0 <= i && i < TAPS) {
                acc[k].x += K[i] * x.x;
                acc[k].y += K[i] * x.y;
            }
        }
    }

    // interior store: c = g + 4, byte offset 16 + 8*t -> 8B aligned, 2-way bank (free)
#pragma unroll
    for (int k = 0; k < OH_T; ++k)
        *reinterpret_cast<float2*>(&mid[k][4 + g0]) = acc[k];

    // mirror halo from registers (H-pass commutes with column mirror):
    //   c=3 <- g=-1 -> mir 0 ; c=2 <- g=-2 -> mir 1 ; c=1 <- g=-3 -> mir 2
    //   c=516 <- g=512 -> mir 511 ; c=517 <- g=513 -> mir 510 ; c=518 <- g=514 -> mir 509
    if (t == 0) {            // owns g=0 (.x), g=1 (.y)
#pragma unroll
        for (int k = 0; k < OH_T; ++k) { mid[k][3] = acc[k].x; mid[k][2] = acc[k].y; }
    } else if (t == 1) {     // owns g=2 (.x)
#pragma unroll
        for (int k = 0; k < OH_T; ++k) mid[k][1] = acc[k].x;
    } else if (t == 255) {   // owns g=510 (.x), g=511 (.y)
#pragma unroll
        for (int k = 0; k < OH_T; ++k) { mid[k][516] = acc[k].y; mid[k][517] = acc[k].x; }
    } else if (t == 254) {   // owns g=509 (.y)
#pragma unroll
        for (int k = 0; k < OH_T; ++k) mid[k][518] = acc[k].y;
    }

    __syncthreads();

    // ---- Phase B: W-pass from LDS. Thread t -> output column t, all 8 rows.
    // Window for output col o: g = 2o-3 .. 2o+4  ->  c = 2o+1 .. 2o+8.
    // LDS reads stride 2 words/lane -> 2 lanes/bank -> conflict-free.
    float* dst = out + ((size_t)bc * H_OUT + oh0) * W_OUT + t;
    const int cb = 2 * t + 1;
#pragma unroll
    for (int row = 0; row < OH_T; ++row) {
        float s = 0.f;
#pragma unroll
        for (int j = 0; j < TAPS; ++j)
            s += K[j] * mid[row][cb + j];
        __builtin_nontemporal_store(s, dst + (size_t)row * W_OUT);
    }
}

extern "C" void kernel_launch(void* const* d_in, const int* in_sizes, int n_in,
                              void* d_out, int out_size, void* d_ws, size_t ws_size,
                              hipStream_t stream) {
    const float* in = (const float*)d_in[0];
    const float* w2 = (const float*)d_in[1];  // (taps,256,1,1,1) flat
    float* out = (float*)d_out;
    (void)d_ws; (void)ws_size;

    // 96 bc * 32 row tiles = 3072 blocks (12 per CU)
    resize_fused<<<BC * 32, 256, 0, stream>>>(in, w2, out);
}